// Round 11
// baseline (26.789 us; speedup 1.0000x reference)
//
#include <hip/hip_runtime.h>
#include <math.h>

typedef float v2f __attribute__((ext_vector_type(2)));

constexpr int Gn = 3072;
constexpr int Hn = 5;
constexpr float EPSf = 1e-6f;
constexpr float L2E  = 1.4426950408889634f;
constexpr float Gf   = 3072.0f;

// ln2^m/m! folded at compile time
#define IV1 0.6931471805599453f
#define IV2 0.2402265069591007f
#define IV3 0.05550410866482158f
#define IV4 0.009618129107628477f

struct __align__(16) Smem {
  float hbuf[Gn];        // hidden state (12 KB)
  float part[15 * 16];   // per-wave folded moment partials (lanes 0-8 used)
  float s1buf[64];       // LN/FC partial sums, zero-padded
  float s2buf[64];
};

__device__ __forceinline__ v2f mk2(float a, float b){ v2f r; r.x=a; r.y=b; return r; }
__device__ __forceinline__ v2f pk_mul(v2f a, v2f b){
  v2f d; asm("v_pk_mul_f32 %0, %1, %2" : "=v"(d) : "v"(a), "v"(b)); return d; }
__device__ __forceinline__ v2f pk_add(v2f a, v2f b){
  v2f d; asm("v_pk_add_f32 %0, %1, %2" : "=v"(d) : "v"(a), "v"(b)); return d; }
__device__ __forceinline__ v2f pk_fma(v2f a, v2f b, v2f c){
  v2f d; asm("v_pk_fma_f32 %0, %1, %2, %3" : "=v"(d) : "v"(a), "v"(b), "v"(c)); return d; }

// PROVEN (R4-R10): wave64 butterfly sum, result in ALL lanes. 4 DPP + 2 shfl.
__device__ __forceinline__ float wave_red(float v) {
  int x;
  x = __builtin_amdgcn_update_dpp(0, __float_as_int(v), 0xB1,  0xF, 0xF, true); // quad xor1
  v += __int_as_float(x);
  x = __builtin_amdgcn_update_dpp(0, __float_as_int(v), 0x4E,  0xF, 0xF, true); // quad xor2
  v += __int_as_float(x);
  x = __builtin_amdgcn_update_dpp(0, __float_as_int(v), 0x141, 0xF, 0xF, true); // row_half_mirror
  v += __int_as_float(x);
  x = __builtin_amdgcn_update_dpp(0, __float_as_int(v), 0x140, 0xF, 0xF, true); // row_mirror
  v += __int_as_float(x);
  v += __shfl_xor(v, 16, 64);
  v += __shfl_xor(v, 32, 64);
  return v;
}

__device__ __forceinline__ float rlf(float v, int lane){
  return __int_as_float(__builtin_amdgcn_readlane(__float_as_int(v), lane)); }

__global__ __launch_bounds__(1024, 4) void net_kernel(
    const float* __restrict__ x,
    const float* __restrict__ WQ1, const float* __restrict__ WK1, const float* __restrict__ WV1,
    const float* __restrict__ WQ2, const float* __restrict__ WK2, const float* __restrict__ WV2,
    const float* __restrict__ WQ3, const float* __restrict__ WK3, const float* __restrict__ WV3,
    const float* __restrict__ W01, const float* __restrict__ W02, const float* __restrict__ W03,
    const float* __restrict__ lna, const float* __restrict__ lnb,
    const float* __restrict__ fcw, const float* __restrict__ fcb,
    float* __restrict__ out)
{
  __shared__ Smem sm;
  const int b = blockIdx.x;
  const int t = threadIdx.x;
  const int w = t >> 6, lane = t & 63;

  const float* WQs[3] = {WQ1, WQ2, WQ3};
  const float* WKs[3] = {WK1, WK2, WK3};
  const float* WVs[3] = {WV1, WV2, WV3};
  const float* W0s[3] = {W01, W02, W03};

  // ---- L2 warm: touch one float per 64B line of every weight array ----
  // (caches are wiped between replays by the harness's ~268MB poison fill;
  //  one parallel burst here replaces serial per-phase cold-miss stalls)
  float warm = 0.f;
  if (t < 960) {
    const int li = t * 16;                 // 960 lines x 16 floats = 15360
    warm = WQ1[li] + WK1[li] + WV1[li]
         + WQ2[li] + WK2[li] + WV2[li]
         + WQ3[li] + WK3[li] + WV3[li];
  }

  // ---- prologue loads (issued alongside the warm burst) ----
  float xx0 = x[b*Gn + t], xx1 = x[b*Gn + t + 1024], xx2 = x[b*Gn + t + 2048];
  const float la0 = lna[t], la1 = lna[t+1024], la2 = lna[t+2048];
  const float lb0 = lnb[t], lb1 = lnb[t+1024], lb2 = lnb[t+2048];
  const float fw00 = fcw[t],      fw01 = fcw[t+1024],      fw02 = fcw[t+2048];
  const float fw10 = fcw[Gn + t], fw11 = fcw[Gn + t+1024], fw12 = fcw[Gn + t+2048];
  sm.hbuf[t] = xx0; sm.hbuf[t+1024] = xx1; sm.hbuf[t+2048] = xx2;
  if (t >= 16 && t < 64) { sm.s1buf[t] = 0.f; sm.s2buf[t] = 0.f; }
  asm volatile("" :: "v"(warm));           // keep warm loads alive
  __syncthreads();

  // hoisted: per-lane combine address (clamped, ALL lanes active)
  const int cli  = (lane < 45) ? lane : 44;
  const int chh  = cli / 9, crr = cli - 9 * chh;
  const int cbase = chh * 48 + crr;        // rows 3h, 3h+1, 3h+2

#pragma unroll
  for (int l = 0; l < 3; ++l) {
    const float* WQ = WQs[l]; const float* WK = WKs[l];
    const float* WV = WVs[l]; const float* W0 = W0s[l];

    // ---- Phase 1: moments (deg-4), 15 waves = 5 heads x 3 slices ----
    if (w < 15) {
      const int h = w / 3, sl = w % 3;
      const float4* xb4 = reinterpret_cast<const float4*>(sm.hbuf) + sl * 256;
      const float4* wk4 = reinterpret_cast<const float4*>(WK + h * Gn) + sl * 256;
      const float4* wv4 = reinterpret_cast<const float4*>(WV + h * Gn) + sl * 256;
      float4 xv[4], kk[4], vv[4];
#pragma unroll
      for (int it = 0; it < 4; ++it) {
        xv[it] = xb4[it * 64 + lane];
        kk[it] = wk4[it * 64 + lane];
        vv[it] = wv4[it * 64 + lane];
      }
      v2f N1 = mk2(0,0), N2 = N1, N3 = N1, N4 = N1;
      v2f M0 = N1, M1 = N1, M2 = N1, M3 = N1, M4 = N1;
      auto accp = [&](v2f xx, v2f wkv, v2f wvv) {
        v2f k = pk_mul(xx, wkv), v = pk_mul(xx, wvv);
        v2f p2 = pk_mul(k, k), p3 = pk_mul(p2, k), p4 = pk_mul(p2, p2);
        N1 = pk_add(N1, k); N2 = pk_add(N2, p2); N3 = pk_add(N3, p3); N4 = pk_add(N4, p4);
        M0 = pk_add(M0, v);
        M1 = pk_fma(k,  v, M1); M2 = pk_fma(p2, v, M2);
        M3 = pk_fma(p3, v, M3); M4 = pk_fma(p4, v, M4);
      };
#pragma unroll
      for (int it = 0; it < 4; ++it) {
        accp(mk2(xv[it].x, xv[it].y), mk2(kk[it].x, kk[it].y), mk2(vv[it].x, vv[it].y));
        accp(mk2(xv[it].z, xv[it].w), mk2(kk[it].z, kk[it].w), mk2(vv[it].z, vv[it].w));
      }
      // butterfly: ALL lanes hold the sum -> fold 1/m!, pack by lane, 1 ds_write
      const float r0 = wave_red(N1.x + N1.y) * IV1;
      const float r1 = wave_red(N2.x + N2.y) * IV2;
      const float r2 = wave_red(N3.x + N3.y) * IV3;
      const float r3 = wave_red(N4.x + N4.y) * IV4;
      const float r4 = wave_red(M0.x + M0.y);
      const float r5 = wave_red(M1.x + M1.y) * IV1;
      const float r6 = wave_red(M2.x + M2.y) * IV2;
      const float r7 = wave_red(M3.x + M3.y) * IV3;
      const float r8 = wave_red(M4.x + M4.y) * IV4;
      float pv = r0;
      pv = (lane == 1) ? r1 : pv;
      pv = (lane == 2) ? r2 : pv;
      pv = (lane == 3) ? r3 : pv;
      pv = (lane == 4) ? r4 : pv;
      pv = (lane == 5) ? r5 : pv;
      pv = (lane == 6) ? r6 : pv;
      pv = (lane == 7) ? r7 : pv;
      pv = (lane == 8) ? r8 : pv;
      if (lane < 9) sm.part[w * 16 + lane] = pv;
    }

    float w0r[Hn];
#pragma unroll
    for (int h = 0; h < Hn; ++h) w0r[h] = W0[h];   // uniform

    __syncthreads();   // B1: partials visible

    // ---- per-wave 3-slice combine (no extra barrier; clamped all-lane reads) ----
    const float cf = sm.part[cbase] + sm.part[cbase + 16] + sm.part[cbase + 32];

    // ---- Phase 3: coeffs -> SGPR via readlane (lanes 0..44 only); zero LDS ----
    float o0 = 0.f, o1 = 0.f, o2 = 0.f;
    const float* wq = WQ + t; const float* wk = WK + t; const float* wv = WV + t;
    float qA = wq[0], qB = wq[1024], qC = wq[2048];
    float kA = wk[0], kB = wk[1024], kC = wk[2048];
    float vA = wv[0], vB = wv[1024], vC = wv[2048];
#pragma unroll
    for (int h = 0; h < Hn; ++h) {
      float nqA, nqB, nqC, nkA, nkB, nkC, nvA, nvB, nvC;
      if (h < Hn - 1) {                              // prefetch next head
        const float* wq2 = WQ + (h+1)*Gn + t;
        const float* wk2 = WK + (h+1)*Gn + t;
        const float* wv2 = WV + (h+1)*Gn + t;
        nqA = wq2[0]; nqB = wq2[1024]; nqC = wq2[2048];
        nkA = wk2[0]; nkB = wk2[1024]; nkC = wk2[2048];
        nvA = wv2[0]; nvB = wv2[1024]; nvC = wv2[2048];
      }
      const float z1 = rlf(cf, h*9+0), z2 = rlf(cf, h*9+1);
      const float z3 = rlf(cf, h*9+2), z4 = rlf(cf, h*9+3);
      const float f0 = rlf(cf, h*9+4), f1 = rlf(cf, h*9+5);
      const float f2 = rlf(cf, h*9+6), f3 = rlf(cf, h*9+7);
      const float f4 = rlf(cf, h*9+8);
      const float w0 = w0r[h];
      auto ev = [&](float xx, float qw, float kw, float vw) -> float {
        const float qe = xx * qw * L2E;
        float Z = z4;
        Z = fmaf(Z, qe, z3); Z = fmaf(Z, qe, z2); Z = fmaf(Z, qe, z1); Z = fmaf(Z, qe, Gf);
        float F = f4;
        F = fmaf(F, qe, f3); F = fmaf(F, qe, f2); F = fmaf(F, qe, f1); F = fmaf(F, qe, f0);
        const float E = __builtin_amdgcn_exp2f(qe * (xx * kw));
        return fmaf(-E, xx * vw, F) * __builtin_amdgcn_rcpf(Z);
      };
      o0 = fmaf(w0, ev(xx0, qA, kA, vA), o0);
      o1 = fmaf(w0, ev(xx1, qB, kB, vB), o1);
      o2 = fmaf(w0, ev(xx2, qC, kC, vC), o2);
      if (h < Hn - 1) {
        qA = nqA; qB = nqB; qC = nqC;
        kA = nkA; kB = nkB; kC = nkC;
        vA = nvA; vB = nvB; vC = nvC;
      }
    }

    // ---- LN: butterfly partials -> padded buf -> butterfly combine ----
    float s1 = o0 + o1 + o2;
    float s2 = fmaf(o0, o0, fmaf(o1, o1, o2 * o2));
    s1 = wave_red(s1); s2 = wave_red(s2);
    if (lane == 0) { sm.s1buf[w] = s1; sm.s2buf[w] = s2; }
    __syncthreads();   // B2: LN partials visible

    const float S1 = wave_red(sm.s1buf[lane]);      // zero-padded -> block sum
    const float S2 = wave_red(sm.s2buf[lane]);
    const float mean = S1 * (1.f / Gf);
    const float var  = fmaxf((S2 - S1 * mean) * (1.f / (Gf - 1.f)), 0.f);
    const float inv  = __builtin_amdgcn_rcpf(sqrtf(var) + EPSf);
    xx0 = xx0 + la0 * (o0 - mean) * inv + lb0;
    xx1 = xx1 + la1 * (o1 - mean) * inv + lb1;
    xx2 = xx2 + la2 * (o2 - mean) * inv + lb2;
    if (l < 2) {
      sm.hbuf[t]      = xx0;
      sm.hbuf[t+1024] = xx1;
      sm.hbuf[t+2048] = xx2;
      __syncthreads(); // B3: next layer reads fresh hbuf
    }
  }

  __syncthreads();     // protect s1buf/s2buf reuse (layer-3 LN reads done)

  // ---- FC head ----
  float s0 = fmaf(xx0, fw00, fmaf(xx1, fw01, xx2 * fw02));
  float s1 = fmaf(xx0, fw10, fmaf(xx1, fw11, xx2 * fw12));
  s0 = wave_red(s0); s1 = wave_red(s1);
  if (lane == 0) { sm.s1buf[w] = s0; sm.s2buf[w] = s1; }
  __syncthreads();
  if (t == 0) {
    float a0 = 0.f, a1 = 0.f;
#pragma unroll
    for (int k = 0; k < 16; ++k) { a0 += sm.s1buf[k]; a1 += sm.s2buf[k]; }
    out[b*2 + 0] = a0 + fcb[0];
    out[b*2 + 1] = a1 + fcb[1];
  }
}

extern "C" void kernel_launch(void* const* d_in, const int* in_sizes, int n_in,
                              void* d_out, int out_size, void* d_ws, size_t ws_size,
                              hipStream_t stream) {
  const float* x    = (const float*)d_in[0];
  const float* WQ1  = (const float*)d_in[1];
  const float* WK1  = (const float*)d_in[2];
  const float* WV1  = (const float*)d_in[3];
  const float* WQ2  = (const float*)d_in[4];
  const float* WK2  = (const float*)d_in[5];
  const float* WV2  = (const float*)d_in[6];
  const float* WQ3  = (const float*)d_in[7];
  const float* WK3  = (const float*)d_in[8];
  const float* WV3  = (const float*)d_in[9];
  const float* W01  = (const float*)d_in[10];
  const float* W02  = (const float*)d_in[11];
  const float* W03  = (const float*)d_in[12];
  const float* ln_a = (const float*)d_in[13];
  const float* ln_b = (const float*)d_in[14];
  const float* fc_w = (const float*)d_in[15];
  const float* fc_b = (const float*)d_in[16];

  net_kernel<<<2, 1024, 0, stream>>>(x,
      WQ1, WK1, WV1, WQ2, WK2, WV2, WQ3, WK3, WV3,
      W01, W02, W03, ln_a, ln_b, fc_w, fc_b, (float*)d_out);
}

// Round 12
// 23.638 us; speedup vs baseline: 1.1333x; 1.1333x over previous
//
#include <hip/hip_runtime.h>
#include <math.h>

typedef float v2f __attribute__((ext_vector_type(2)));

constexpr int Gn = 3072;
constexpr int Hn = 5;
constexpr float EPSf = 1e-6f;
constexpr float L2E  = 1.4426950408889634f;
constexpr float Gf   = 3072.0f;

// ln2^m/m! folded at compile time
#define IV1 0.6931471805599453f
#define IV2 0.2402265069591007f
#define IV3 0.05550410866482158f
#define IV4 0.009618129107628477f

struct __align__(16) Smem {
  float hbuf[Gn];        // hidden state (12 KB)
  float part[15 * 16];   // per-wave folded moment partials (lanes 0-8 used)
  float coeffbuf[64];    // combined coeffs, zero-padded to 64
  float s1buf[64];       // LN/FC partial sums, zero-padded
  float s2buf[64];
};

__device__ __forceinline__ v2f mk2(float a, float b){ v2f r; r.x=a; r.y=b; return r; }
__device__ __forceinline__ v2f pk_mul(v2f a, v2f b){
  v2f d; asm("v_pk_mul_f32 %0, %1, %2" : "=v"(d) : "v"(a), "v"(b)); return d; }
__device__ __forceinline__ v2f pk_add(v2f a, v2f b){
  v2f d; asm("v_pk_add_f32 %0, %1, %2" : "=v"(d) : "v"(a), "v"(b)); return d; }
__device__ __forceinline__ v2f pk_fma(v2f a, v2f b, v2f c){
  v2f d; asm("v_pk_fma_f32 %0, %1, %2, %3" : "=v"(d) : "v"(a), "v"(b), "v"(c)); return d; }

// PROVEN (R4-R10): wave64 butterfly sum, result in ALL lanes. 4 DPP + 2 shfl.
__device__ __forceinline__ float wave_red(float v) {
  int x;
  x = __builtin_amdgcn_update_dpp(0, __float_as_int(v), 0xB1,  0xF, 0xF, true); // quad xor1
  v += __int_as_float(x);
  x = __builtin_amdgcn_update_dpp(0, __float_as_int(v), 0x4E,  0xF, 0xF, true); // quad xor2
  v += __int_as_float(x);
  x = __builtin_amdgcn_update_dpp(0, __float_as_int(v), 0x141, 0xF, 0xF, true); // row_half_mirror
  v += __int_as_float(x);
  x = __builtin_amdgcn_update_dpp(0, __float_as_int(v), 0x140, 0xF, 0xF, true); // row_mirror
  v += __int_as_float(x);
  v += __shfl_xor(v, 16, 64);
  v += __shfl_xor(v, 32, 64);
  return v;
}

__device__ __forceinline__ float rlf(float v, int lane){
  return __int_as_float(__builtin_amdgcn_readlane(__float_as_int(v), lane)); }

__global__ __launch_bounds__(1024, 4) void net_kernel(
    const float* __restrict__ x,
    const float* __restrict__ WQ1, const float* __restrict__ WK1, const float* __restrict__ WV1,
    const float* __restrict__ WQ2, const float* __restrict__ WK2, const float* __restrict__ WV2,
    const float* __restrict__ WQ3, const float* __restrict__ WK3, const float* __restrict__ WV3,
    const float* __restrict__ W01, const float* __restrict__ W02, const float* __restrict__ W03,
    const float* __restrict__ lna, const float* __restrict__ lnb,
    const float* __restrict__ fcw, const float* __restrict__ fcb,
    float* __restrict__ out)
{
  const int blk = blockIdx.x;

  // ---- helper blocks (2..31): LLC-warm the 9 weight arrays, then exit ----
  // Pure reads on OTHER CUs; no stores, no sync. Timing-only hint: turns the
  // compute blocks' layer-2/3 cold HBM misses (~900cy) into LLC hits (~450cy).
  if (blk >= 2) {
    const int hb = blk - 2;              // 0..29
    const int tt = threadIdx.x;
    if (tt < 128) {                      // 30 blocks x 128 f4 = 3840 f4 = 15360 floats/array
      const float* Ws[9] = {WQ1, WK1, WV1, WQ2, WK2, WV2, WQ3, WK3, WV3};
      float a0 = 0.f, a1 = 0.f, a2 = 0.f, a3 = 0.f;
#pragma unroll
      for (int a = 0; a < 9; ++a) {
        const float4 v = *(reinterpret_cast<const float4*>(Ws[a]) + hb * 128 + tt);
        a0 += v.x; a1 += v.y; a2 += v.z; a3 += v.w;
      }
      asm volatile("" :: "v"(a0), "v"(a1), "v"(a2), "v"(a3));  // DCE-guard
    }
    return;
  }

  __shared__ Smem sm;
  const int b = blk;
  const int t = threadIdx.x;
  const int w = t >> 6, lane = t & 63;

  const float* WQs[3] = {WQ1, WQ2, WQ3};
  const float* WKs[3] = {WK1, WK2, WK3};
  const float* WVs[3] = {WV1, WV2, WV3};
  const float* W0s[3] = {W01, W02, W03};

  // ---- prologue ----
  float xx0 = x[b*Gn + t], xx1 = x[b*Gn + t + 1024], xx2 = x[b*Gn + t + 2048];
  const float la0 = lna[t], la1 = lna[t+1024], la2 = lna[t+2048];
  const float lb0 = lnb[t], lb1 = lnb[t+1024], lb2 = lnb[t+2048];
  const float fw00 = fcw[t],      fw01 = fcw[t+1024],      fw02 = fcw[t+2048];
  const float fw10 = fcw[Gn + t], fw11 = fcw[Gn + t+1024], fw12 = fcw[Gn + t+2048];
  sm.hbuf[t] = xx0; sm.hbuf[t+1024] = xx1; sm.hbuf[t+2048] = xx2;
  if (t >= 45 && t < 64) sm.coeffbuf[t] = 0.f;       // pad once; never rewritten
  if (t >= 16 && t < 64) { sm.s1buf[t] = 0.f; sm.s2buf[t] = 0.f; }
  __syncthreads();

#pragma unroll
  for (int l = 0; l < 3; ++l) {
    const float* WQ = WQs[l]; const float* WK = WKs[l];
    const float* WV = WVs[l]; const float* W0 = W0s[l];

    // ---- Phase 1: moments (deg-4), 15 waves = 5 heads x 3 slices ----
    if (w < 15) {
      const int h = w / 3, sl = w % 3;
      const float4* xb4 = reinterpret_cast<const float4*>(sm.hbuf) + sl * 256;
      const float4* wk4 = reinterpret_cast<const float4*>(WK + h * Gn) + sl * 256;
      const float4* wv4 = reinterpret_cast<const float4*>(WV + h * Gn) + sl * 256;
      float4 xv[4], kk[4], vv[4];
#pragma unroll
      for (int it = 0; it < 4; ++it) {
        xv[it] = xb4[it * 64 + lane];
        kk[it] = wk4[it * 64 + lane];
        vv[it] = wv4[it * 64 + lane];
      }
      v2f N1 = mk2(0,0), N2 = N1, N3 = N1, N4 = N1;
      v2f M0 = N1, M1 = N1, M2 = N1, M3 = N1, M4 = N1;
      auto accp = [&](v2f xx, v2f wkv, v2f wvv) {
        v2f k = pk_mul(xx, wkv), v = pk_mul(xx, wvv);
        v2f p2 = pk_mul(k, k), p3 = pk_mul(p2, k), p4 = pk_mul(p2, p2);
        N1 = pk_add(N1, k); N2 = pk_add(N2, p2); N3 = pk_add(N3, p3); N4 = pk_add(N4, p4);
        M0 = pk_add(M0, v);
        M1 = pk_fma(k,  v, M1); M2 = pk_fma(p2, v, M2);
        M3 = pk_fma(p3, v, M3); M4 = pk_fma(p4, v, M4);
      };
#pragma unroll
      for (int it = 0; it < 4; ++it) {
        accp(mk2(xv[it].x, xv[it].y), mk2(kk[it].x, kk[it].y), mk2(vv[it].x, vv[it].y));
        accp(mk2(xv[it].z, xv[it].w), mk2(kk[it].z, kk[it].w), mk2(vv[it].z, vv[it].w));
      }
      // butterfly: ALL lanes hold the sum -> fold 1/m!, pack by lane, 1 ds_write
      const float r0 = wave_red(N1.x + N1.y) * IV1;
      const float r1 = wave_red(N2.x + N2.y) * IV2;
      const float r2 = wave_red(N3.x + N3.y) * IV3;
      const float r3 = wave_red(N4.x + N4.y) * IV4;
      const float r4 = wave_red(M0.x + M0.y);
      const float r5 = wave_red(M1.x + M1.y) * IV1;
      const float r6 = wave_red(M2.x + M2.y) * IV2;
      const float r7 = wave_red(M3.x + M3.y) * IV3;
      const float r8 = wave_red(M4.x + M4.y) * IV4;
      float pv = r0;
      pv = (lane == 1) ? r1 : pv;
      pv = (lane == 2) ? r2 : pv;
      pv = (lane == 3) ? r3 : pv;
      pv = (lane == 4) ? r4 : pv;
      pv = (lane == 5) ? r5 : pv;
      pv = (lane == 6) ? r6 : pv;
      pv = (lane == 7) ? r7 : pv;
      pv = (lane == 8) ? r8 : pv;
      if (lane < 9) sm.part[w * 16 + lane] = pv;
    }

    float w0r[Hn];
#pragma unroll
    for (int h = 0; h < Hn; ++h) w0r[h] = W0[h];   // uniform

    __syncthreads();   // B1: partials visible

    // ---- Phase 2 (wave 0 only): combine 3 slices -> coeffbuf[0..44] ----
    if (t < 45) {
      const int h = t / 9, r = t - 9 * h;
      const int base = h * 48 + r;                  // rows 3h,3h+1,3h+2
      sm.coeffbuf[t] = sm.part[base] + sm.part[base + 16] + sm.part[base + 32];
    }
    __syncthreads();   // B2: coeffs visible

    // ---- Phase 3: 1 non-divergent LDS read/wave; coeffs -> SGPR via readlane ----
    const float cf = sm.coeffbuf[lane];             // zero-padded, all lanes
    float o0 = 0.f, o1 = 0.f, o2 = 0.f;
    const float* wq = WQ + t; const float* wk = WK + t; const float* wv = WV + t;
    float qA = wq[0], qB = wq[1024], qC = wq[2048];
    float kA = wk[0], kB = wk[1024], kC = wk[2048];
    float vA = wv[0], vB = wv[1024], vC = wv[2048];
#pragma unroll
    for (int h = 0; h < Hn; ++h) {
      float nqA, nqB, nqC, nkA, nkB, nkC, nvA, nvB, nvC;
      if (h < Hn - 1) {                              // prefetch next head
        const float* wq2 = WQ + (h+1)*Gn + t;
        const float* wk2 = WK + (h+1)*Gn + t;
        const float* wv2 = WV + (h+1)*Gn + t;
        nqA = wq2[0]; nqB = wq2[1024]; nqC = wq2[2048];
        nkA = wk2[0]; nkB = wk2[1024]; nkC = wk2[2048];
        nvA = wv2[0]; nvB = wv2[1024]; nvC = wv2[2048];
      }
      const float z1 = rlf(cf, h*9+0), z2 = rlf(cf, h*9+1);
      const float z3 = rlf(cf, h*9+2), z4 = rlf(cf, h*9+3);
      const float f0 = rlf(cf, h*9+4), f1 = rlf(cf, h*9+5);
      const float f2 = rlf(cf, h*9+6), f3 = rlf(cf, h*9+7);
      const float f4 = rlf(cf, h*9+8);
      const float w0 = w0r[h];
      auto ev = [&](float xx, float qw, float kw, float vw) -> float {
        const float qe = xx * qw * L2E;
        float Z = z4;
        Z = fmaf(Z, qe, z3); Z = fmaf(Z, qe, z2); Z = fmaf(Z, qe, z1); Z = fmaf(Z, qe, Gf);
        float F = f4;
        F = fmaf(F, qe, f3); F = fmaf(F, qe, f2); F = fmaf(F, qe, f1); F = fmaf(F, qe, f0);
        const float E = __builtin_amdgcn_exp2f(qe * (xx * kw));
        return fmaf(-E, xx * vw, F) * __builtin_amdgcn_rcpf(Z);
      };
      o0 = fmaf(w0, ev(xx0, qA, kA, vA), o0);
      o1 = fmaf(w0, ev(xx1, qB, kB, vB), o1);
      o2 = fmaf(w0, ev(xx2, qC, kC, vC), o2);
      if (h < Hn - 1) {
        qA = nqA; qB = nqB; qC = nqC;
        kA = nkA; kB = nkB; kC = nkC;
        vA = nvA; vB = nvB; vC = nvC;
      }
    }

    // ---- LN: butterfly partials -> padded buf -> butterfly combine ----
    float s1 = o0 + o1 + o2;
    float s2 = fmaf(o0, o0, fmaf(o1, o1, o2 * o2));
    s1 = wave_red(s1); s2 = wave_red(s2);
    if (lane == 0) { sm.s1buf[w] = s1; sm.s2buf[w] = s2; }
    __syncthreads();   // B3: LN partials visible

    const float S1 = wave_red(sm.s1buf[lane]);      // zero-padded -> block sum
    const float S2 = wave_red(sm.s2buf[lane]);
    const float mean = S1 * (1.f / Gf);
    const float var  = fmaxf((S2 - S1 * mean) * (1.f / (Gf - 1.f)), 0.f);
    const float inv  = __builtin_amdgcn_rcpf(sqrtf(var) + EPSf);
    xx0 = xx0 + la0 * (o0 - mean) * inv + lb0;
    xx1 = xx1 + la1 * (o1 - mean) * inv + lb1;
    xx2 = xx2 + la2 * (o2 - mean) * inv + lb2;
    if (l < 2) {
      sm.hbuf[t]      = xx0;
      sm.hbuf[t+1024] = xx1;
      sm.hbuf[t+2048] = xx2;
      __syncthreads(); // B4: next layer reads fresh hbuf
    }
  }

  __syncthreads();     // protect s1buf/s2buf reuse (LN reads done)

  // ---- FC head ----
  float s0 = fmaf(xx0, fw00, fmaf(xx1, fw01, xx2 * fw02));
  float s1 = fmaf(xx0, fw10, fmaf(xx1, fw11, xx2 * fw12));
  s0 = wave_red(s0); s1 = wave_red(s1);
  if (lane == 0) { sm.s1buf[w] = s0; sm.s2buf[w] = s1; }
  __syncthreads();
  if (t == 0) {
    float a0 = 0.f, a1 = 0.f;
#pragma unroll
    for (int k = 0; k < 16; ++k) { a0 += sm.s1buf[k]; a1 += sm.s2buf[k]; }
    out[b*2 + 0] = a0 + fcb[0];
    out[b*2 + 1] = a1 + fcb[1];
  }
}

extern "C" void kernel_launch(void* const* d_in, const int* in_sizes, int n_in,
                              void* d_out, int out_size, void* d_ws, size_t ws_size,
                              hipStream_t stream) {
  const float* x    = (const float*)d_in[0];
  const float* WQ1  = (const float*)d_in[1];
  const float* WK1  = (const float*)d_in[2];
  const float* WV1  = (const float*)d_in[3];
  const float* WQ2  = (const float*)d_in[4];
  const float* WK2  = (const float*)d_in[5];
  const float* WV2  = (const float*)d_in[6];
  const float* WQ3  = (const float*)d_in[7];
  const float* WK3  = (const float*)d_in[8];
  const float* WV3  = (const float*)d_in[9];
  const float* W01  = (const float*)d_in[10];
  const float* W02  = (const float*)d_in[11];
  const float* W03  = (const float*)d_in[12];
  const float* ln_a = (const float*)d_in[13];
  const float* ln_b = (const float*)d_in[14];
  const float* fc_w = (const float*)d_in[15];
  const float* fc_b = (const float*)d_in[16];

  // blocks 0-1: compute (one per batch). blocks 2-31: LLC-warm helpers.
  net_kernel<<<32, 1024, 0, stream>>>(x,
      WQ1, WK1, WV1, WQ2, WK2, WV2, WQ3, WK3, WV3,
      W01, W02, W03, ln_a, ln_b, fc_w, fc_b, (float*)d_out);
}